// Round 1
// baseline (2046.480 us; speedup 1.0000x reference)
//
#include <hip/hip_runtime.h>

#define EPS 1e-5f
#define BATCH 524288
#define BLK 256
#define NBLK (BATCH / BLK) // 2048

__device__ __forceinline__ float sigm(float x) {
    return __builtin_amdgcn_rcpf(1.0f + __expf(-x));
}
__device__ __forceinline__ float tanh_f(float x) {
    // tanh(x) = 1 - 2/(1+e^{2x}); saturates correctly for |x| large.
    return 1.0f - 2.0f * __builtin_amdgcn_rcpf(1.0f + __expf(2.0f * x));
}
__device__ __forceinline__ float wave_reduce(float v) {
    #pragma unroll
    for (int o = 32; o; o >>= 1) v += __shfl_down(v, o, 64);
    return v;
}

// ---------------- Kernel 1: per-channel sums of x ----------------
__global__ __launch_bounds__(BLK) void k_reduce_x(const float* __restrict__ x,
                                                  float* __restrict__ part1) {
    int b = blockIdx.x * BLK + threadIdx.x;
    const float4* xp = (const float4*)(x + (size_t)b * 24);
    float s[6], q[6];
    #pragma unroll
    for (int t = 0; t < 6; ++t) {
        float4 v = xp[t];
        s[t] = (v.x + v.y) + (v.z + v.w);
        q[t] = (v.x * v.x + v.y * v.y) + (v.z * v.z + v.w * v.w);
    }
    __shared__ float red[4 * 12];
    int wid = threadIdx.x >> 6, lane = threadIdx.x & 63;
    #pragma unroll
    for (int c = 0; c < 6; ++c) {
        float rs = wave_reduce(s[c]);
        float rq = wave_reduce(q[c]);
        if (lane == 0) { red[wid * 12 + c] = rs; red[wid * 12 + 6 + c] = rq; }
    }
    __syncthreads();
    if (threadIdx.x < 12) {
        float tot = red[threadIdx.x] + red[12 + threadIdx.x] +
                    red[24 + threadIdx.x] + red[36 + threadIdx.x];
        part1[blockIdx.x * 12 + threadIdx.x] = tot;
    }
}

// ---------------- Kernel 2: finalize BN1 stats -> a[t], b2[t] ----------------
__global__ __launch_bounds__(BLK) void k_stats1(const float* __restrict__ part1,
                                                const float* __restrict__ gamma,
                                                const float* __restrict__ beta,
                                                float* __restrict__ stats) {
    float acc[12];
    #pragma unroll
    for (int c = 0; c < 12; ++c) acc[c] = 0.f;
    for (int p = threadIdx.x; p < NBLK; p += BLK) {
        #pragma unroll
        for (int c = 0; c < 12; ++c) acc[c] += part1[p * 12 + c];
    }
    __shared__ float red[4 * 12];
    __shared__ float tot[12];
    int wid = threadIdx.x >> 6, lane = threadIdx.x & 63;
    #pragma unroll
    for (int c = 0; c < 12; ++c) {
        float r = wave_reduce(acc[c]);
        if (lane == 0) red[wid * 12 + c] = r;
    }
    __syncthreads();
    if (threadIdx.x < 12) {
        tot[threadIdx.x] = red[threadIdx.x] + red[12 + threadIdx.x] +
                           red[24 + threadIdx.x] + red[36 + threadIdx.x];
    }
    __syncthreads();
    if (threadIdx.x < 6) {
        int t = threadIdx.x;
        const float N = (float)BATCH * 4.0f;
        float mean = tot[t] / N;
        float var = tot[6 + t] / N - mean * mean;
        float inv = rsqrtf(var + EPS);
        float a = gamma[t] * inv;
        stats[t] = a;
        stats[6 + t] = beta[t] - mean * a;
    }
}

// ---------------- Kernel 3: fused BN1-apply + 2-layer LSTM + head dot ----------------
__global__ __launch_bounds__(BLK) void k_lstm(
    const float* __restrict__ x,
    const float* __restrict__ Wih0, const float* __restrict__ Whh0,
    const float* __restrict__ bih0, const float* __restrict__ bhh0,
    const float* __restrict__ Wih1, const float* __restrict__ Whh1,
    const float* __restrict__ bih1, const float* __restrict__ bhh1,
    const float* __restrict__ Wout,
    const float* __restrict__ stats,
    float* __restrict__ dotout, float* __restrict__ part2) {
    // Transposed weights in LDS: [k][gate-row 0..79] so a fixed-k slice is 80
    // contiguous floats -> 20 uniform (broadcast) ds_read_b128 per k.
    __shared__ __align__(16) float sWih0T[4 * 80];
    __shared__ __align__(16) float sWhh0T[20 * 80];
    __shared__ __align__(16) float sWih1T[20 * 80];
    __shared__ __align__(16) float sWhh1T[20 * 80];
    __shared__ float sB0[80];
    __shared__ float sB1[80];
    __shared__ float sWo[20];
    __shared__ float sA[12];
    // Per-thread h state in LDS (stride 21: odd -> 2-way bank alias = free).
    __shared__ float sH0[BLK * 21];
    __shared__ float sH1[BLK * 21];

    const int tid = threadIdx.x;
    for (int m = tid; m < 320; m += BLK) sWih0T[(m & 3) * 80 + (m >> 2)] = Wih0[m];
    for (int m = tid; m < 1600; m += BLK) { int g = m / 20, k = m - g * 20; sWhh0T[k * 80 + g] = Whh0[m]; }
    for (int m = tid; m < 1600; m += BLK) { int g = m / 20, k = m - g * 20; sWih1T[k * 80 + g] = Wih1[m]; }
    for (int m = tid; m < 1600; m += BLK) { int g = m / 20, k = m - g * 20; sWhh1T[k * 80 + g] = Whh1[m]; }
    for (int m = tid; m < 80; m += BLK) { sB0[m] = bih0[m] + bhh0[m]; sB1[m] = bih1[m] + bhh1[m]; }
    if (tid < 20) sWo[tid] = Wout[tid];
    if (tid < 12) sA[tid] = stats[tid];
    __syncthreads();

    const int b = blockIdx.x * BLK + tid;
    const float4* xp = (const float4*)(x + (size_t)b * 24);

    float* h0p = &sH0[tid * 21];
    float* h1p = &sH1[tid * 21];
    float c0[20], c1[20];
    #pragma unroll
    for (int j = 0; j < 20; ++j) { c0[j] = 0.f; c1[j] = 0.f; h0p[j] = 0.f; h1p[j] = 0.f; }

    float ai[20], af[20], ag[20], ao[20];
    // accumulate 4 gate vectors (j static via unrolled inner loop)
    auto gate_fma = [&](const float* wrow, float s) {
        const float4* w4 = (const float4*)wrow;
        #pragma unroll
        for (int j4 = 0; j4 < 5; ++j4) {
            float4 wi = w4[j4], wf = w4[5 + j4], wg = w4[10 + j4], wo = w4[15 + j4];
            ai[4 * j4 + 0] += s * wi.x; ai[4 * j4 + 1] += s * wi.y; ai[4 * j4 + 2] += s * wi.z; ai[4 * j4 + 3] += s * wi.w;
            af[4 * j4 + 0] += s * wf.x; af[4 * j4 + 1] += s * wf.y; af[4 * j4 + 2] += s * wf.z; af[4 * j4 + 3] += s * wf.w;
            ag[4 * j4 + 0] += s * wg.x; ag[4 * j4 + 1] += s * wg.y; ag[4 * j4 + 2] += s * wg.z; ag[4 * j4 + 3] += s * wg.w;
            ao[4 * j4 + 0] += s * wo.x; ao[4 * j4 + 1] += s * wo.y; ao[4 * j4 + 2] += s * wo.z; ao[4 * j4 + 3] += s * wo.w;
        }
    };

    #pragma unroll 1
    for (int t = 0; t < 6; ++t) {
        float at = sA[t], bt = sA[6 + t];
        float4 xv = xp[t];
        float xn[4];
        xn[0] = at * xv.x + bt; xn[1] = at * xv.y + bt;
        xn[2] = at * xv.z + bt; xn[3] = at * xv.w + bt;

        // ---- layer 0 ----
        #pragma unroll
        for (int j = 0; j < 20; ++j) { ai[j] = sB0[j]; af[j] = sB0[20 + j]; ag[j] = sB0[40 + j]; ao[j] = sB0[60 + j]; }
        #pragma unroll
        for (int k = 0; k < 4; ++k) gate_fma(&sWih0T[k * 80], xn[k]);
        #pragma unroll 4
        for (int k = 0; k < 20; ++k) gate_fma(&sWhh0T[k * 80], h0p[k]);
        #pragma unroll
        for (int j = 0; j < 20; ++j) {
            float ii = sigm(ai[j]), ff = sigm(af[j]), gg = tanh_f(ag[j]), oo = sigm(ao[j]);
            c0[j] = ff * c0[j] + ii * gg;
            h0p[j] = oo * tanh_f(c0[j]);
        }

        // ---- layer 1 (input = new h0) ----
        #pragma unroll
        for (int j = 0; j < 20; ++j) { ai[j] = sB1[j]; af[j] = sB1[20 + j]; ag[j] = sB1[40 + j]; ao[j] = sB1[60 + j]; }
        #pragma unroll 2
        for (int k = 0; k < 20; ++k) {
            gate_fma(&sWih1T[k * 80], h0p[k]);
            gate_fma(&sWhh1T[k * 80], h1p[k]);
        }
        #pragma unroll
        for (int j = 0; j < 20; ++j) {
            float ii = sigm(ai[j]), ff = sigm(af[j]), gg = tanh_f(ag[j]), oo = sigm(ao[j]);
            c1[j] = ff * c1[j] + ii * gg;
            h1p[j] = oo * tanh_f(c1[j]);
        }
    }

    // final hidden of layer1 = h2[:,5,:] -> head dot + BN2 partial sums
    float sum = 0.f, sumsq = 0.f, dot = 0.f;
    #pragma unroll
    for (int j = 0; j < 20; ++j) {
        float v = h1p[j];
        sum += v; sumsq += v * v; dot += v * sWo[j];
    }
    dotout[b] = dot;
    sum = wave_reduce(sum);
    sumsq = wave_reduce(sumsq);
    __syncthreads();  // done with sH0; reuse as reduce scratch
    float* red = sH0;
    int wid = tid >> 6, lane = tid & 63;
    if (lane == 0) { red[wid] = sum; red[4 + wid] = sumsq; }
    __syncthreads();
    if (tid == 0) {
        part2[blockIdx.x * 2 + 0] = red[0] + red[1] + red[2] + red[3];
        part2[blockIdx.x * 2 + 1] = red[4] + red[5] + red[6] + red[7];
    }
}

// ---------------- Kernel 4: finalize BN2 stats -> s1, s2 ----------------
__global__ __launch_bounds__(BLK) void k_stats2(const float* __restrict__ part2,
                                                const float* __restrict__ gamma,
                                                const float* __restrict__ beta,
                                                const float* __restrict__ Wout,
                                                const float* __restrict__ bout,
                                                float* __restrict__ stats) {
    float s = 0.f, q = 0.f;
    for (int p = threadIdx.x; p < NBLK; p += BLK) { s += part2[2 * p]; q += part2[2 * p + 1]; }
    __shared__ float red[8];
    s = wave_reduce(s);
    q = wave_reduce(q);
    int wid = threadIdx.x >> 6, lane = threadIdx.x & 63;
    if (lane == 0) { red[wid] = s; red[4 + wid] = q; }
    __syncthreads();
    if (threadIdx.x == 0) {
        float S = red[0] + red[1] + red[2] + red[3];
        float Q = red[4] + red[5] + red[6] + red[7];
        const float N = (float)BATCH * 20.0f;
        float m = S / N, var = Q / N - m * m;
        float inv = rsqrtf(var + EPS);
        float s1 = gamma[5] * inv;
        float sw = 0.f;
        for (int h = 0; h < 20; ++h) sw += Wout[h];
        stats[12] = s1;
        stats[13] = (beta[5] - m * s1) * sw + bout[0];
    }
}

// ---------------- Kernel 5: out = s1*dot + s2 (in place) ----------------
__global__ __launch_bounds__(BLK) void k_out(float* __restrict__ out,
                                             const float* __restrict__ stats) {
    int i = blockIdx.x * BLK + threadIdx.x;
    out[i] = stats[12] * out[i] + stats[13];
}

extern "C" void kernel_launch(void* const* d_in, const int* in_sizes, int n_in,
                              void* d_out, int out_size, void* d_ws, size_t ws_size,
                              hipStream_t stream) {
    const float* x     = (const float*)d_in[0];
    const float* gamma = (const float*)d_in[1];
    const float* beta  = (const float*)d_in[2];
    const float* Wih0  = (const float*)d_in[3];
    const float* Whh0  = (const float*)d_in[4];
    const float* bih0  = (const float*)d_in[5];
    const float* bhh0  = (const float*)d_in[6];
    const float* Wih1  = (const float*)d_in[7];
    const float* Whh1  = (const float*)d_in[8];
    const float* bih1  = (const float*)d_in[9];
    const float* bhh1  = (const float*)d_in[10];
    const float* Wout  = (const float*)d_in[11];
    const float* bout  = (const float*)d_in[12];
    float* out = (float*)d_out;
    float* ws = (float*)d_ws;

    float* part1 = ws;              // NBLK*12
    float* part2 = ws + NBLK * 12;  // NBLK*2
    float* stats = ws + NBLK * 14;  // 16 floats

    k_reduce_x<<<NBLK, BLK, 0, stream>>>(x, part1);
    k_stats1<<<1, BLK, 0, stream>>>(part1, gamma, beta, stats);
    k_lstm<<<NBLK, BLK, 0, stream>>>(x, Wih0, Whh0, bih0, bhh0,
                                     Wih1, Whh1, bih1, bhh1, Wout,
                                     stats, out, part2);
    k_stats2<<<1, BLK, 0, stream>>>(part2, gamma, beta, Wout, bout, stats);
    k_out<<<NBLK, BLK, 0, stream>>>(out, stats);
}

// Round 2
// 769.977 us; speedup vs baseline: 2.6578x; 2.6578x over previous
//
#include <hip/hip_runtime.h>

#define EPS 1e-5f
#define BATCH 524288
#define BLK 256
#define NBLK (BATCH / BLK)   // 2048 blocks for k_lstm
#define RBLK 256             // blocks for k_reduce_x

// -------- workspace float offsets --------
#define OFF_IH0 0                   // 4*80   W_ih0^T [k][gate]
#define OFF_HH0 320                 // 20*80  W_hh0^T
#define OFF_IH1 1920                // 20*80  W_ih1^T
#define OFF_HH1 3520                // 20*80  W_hh1^T
#define OFF_B0  5120                // 80     b_ih0+b_hh0
#define OFF_B1  5200                // 80
#define OFF_P1  5376                // RBLK*12 partials for BN1
#define OFF_P2  (OFF_P1 + RBLK*12)  // NBLK*2 partials for BN2
#define OFF_ST  (OFF_P2 + NBLK*2)   // 16 floats: a[6], b[6], s1, s2

__device__ __forceinline__ float sigm(float x) {
    return __builtin_amdgcn_rcpf(1.0f + __expf(-x));
}
__device__ __forceinline__ float tanh_f(float x) {
    return 1.0f - 2.0f * __builtin_amdgcn_rcpf(1.0f + __expf(2.0f * x));
}
__device__ __forceinline__ float wave_reduce(float v) {
    #pragma unroll
    for (int o = 32; o; o >>= 1) v += __shfl_down(v, o, 64);
    return v;
}

// ---------------- Kernel 0: transpose weights into ws ----------------
__global__ __launch_bounds__(BLK) void k_prep(
    const float* __restrict__ Wih0, const float* __restrict__ Whh0,
    const float* __restrict__ bih0, const float* __restrict__ bhh0,
    const float* __restrict__ Wih1, const float* __restrict__ Whh1,
    const float* __restrict__ bih1, const float* __restrict__ bhh1,
    float* __restrict__ wsT) {
    int tid = threadIdx.x;
    for (int m = tid; m < 320; m += BLK) {
        int k = m / 80, g = m % 80;
        wsT[OFF_IH0 + m] = Wih0[g * 4 + k];
    }
    for (int m = tid; m < 1600; m += BLK) {
        int k = m / 80, g = m % 80;
        wsT[OFF_HH0 + m] = Whh0[g * 20 + k];
        wsT[OFF_IH1 + m] = Wih1[g * 20 + k];
        wsT[OFF_HH1 + m] = Whh1[g * 20 + k];
    }
    for (int m = tid; m < 80; m += BLK) {
        wsT[OFF_B0 + m] = bih0[m] + bhh0[m];
        wsT[OFF_B1 + m] = bih1[m] + bhh1[m];
    }
}

// ---------------- Kernel 1: per-channel sums of x (grid-stride) ----------------
__global__ __launch_bounds__(BLK) void k_reduce_x(const float* __restrict__ x,
                                                  float* __restrict__ part1) {
    float s[6], q[6];
    #pragma unroll
    for (int t = 0; t < 6; ++t) { s[t] = 0.f; q[t] = 0.f; }
    for (int b = blockIdx.x * BLK + threadIdx.x; b < BATCH; b += RBLK * BLK) {
        const float4* xp = (const float4*)(x + (size_t)b * 24);
        #pragma unroll
        for (int t = 0; t < 6; ++t) {
            float4 v = xp[t];
            s[t] += (v.x + v.y) + (v.z + v.w);
            q[t] += (v.x * v.x + v.y * v.y) + (v.z * v.z + v.w * v.w);
        }
    }
    __shared__ float red[4 * 12];
    int wid = threadIdx.x >> 6, lane = threadIdx.x & 63;
    #pragma unroll
    for (int c = 0; c < 6; ++c) {
        float rs = wave_reduce(s[c]);
        float rq = wave_reduce(q[c]);
        if (lane == 0) { red[wid * 12 + c] = rs; red[wid * 12 + 6 + c] = rq; }
    }
    __syncthreads();
    if (threadIdx.x < 12) {
        float tot = red[threadIdx.x] + red[12 + threadIdx.x] +
                    red[24 + threadIdx.x] + red[36 + threadIdx.x];
        part1[blockIdx.x * 12 + threadIdx.x] = tot;
    }
}

// ---------------- Kernel 2: finalize BN1 stats ----------------
__global__ __launch_bounds__(BLK) void k_stats1(const float* __restrict__ part1,
                                                const float* __restrict__ gamma,
                                                const float* __restrict__ beta,
                                                float* __restrict__ stats) {
    float acc[12];
    #pragma unroll
    for (int c = 0; c < 12; ++c) acc[c] = 0.f;
    for (int p = threadIdx.x; p < RBLK; p += BLK) {
        #pragma unroll
        for (int c = 0; c < 12; ++c) acc[c] += part1[p * 12 + c];
    }
    __shared__ float red[4 * 12];
    __shared__ float tot[12];
    int wid = threadIdx.x >> 6, lane = threadIdx.x & 63;
    #pragma unroll
    for (int c = 0; c < 12; ++c) {
        float r = wave_reduce(acc[c]);
        if (lane == 0) red[wid * 12 + c] = r;
    }
    __syncthreads();
    if (threadIdx.x < 12) {
        tot[threadIdx.x] = red[threadIdx.x] + red[12 + threadIdx.x] +
                           red[24 + threadIdx.x] + red[36 + threadIdx.x];
    }
    __syncthreads();
    if (threadIdx.x < 6) {
        int t = threadIdx.x;
        const float N = (float)BATCH * 4.0f;
        float mean = tot[t] / N;
        float var = tot[6 + t] / N - mean * mean;
        float inv = rsqrtf(var + EPS);
        float a = gamma[t] * inv;
        stats[t] = a;
        stats[6 + t] = beta[t] - mean * a;
    }
}

// ---------------- Kernel 3: fused BN1 + 2-layer LSTM + head dot ----------------
// Weights are wave-uniform -> scalar (s_load) operands. Per-lane h state in LDS.
__global__ __launch_bounds__(BLK, 2) void k_lstm(
    const float* __restrict__ x,
    const float* __restrict__ wsT,
    const float* __restrict__ Wout,
    const float* __restrict__ stats,
    float* __restrict__ dotout, float* __restrict__ part2) {
    // stride 21 (odd): 64 lanes at fixed k hit 32 banks 2-way -> conflict-free
    __shared__ float sH0[BLK * 21];
    __shared__ float sH1[BLK * 21];

    const int tid = threadIdx.x;
    const int b = blockIdx.x * BLK + tid;
    float* h0p = &sH0[tid * 21];
    float* h1p = &sH1[tid * 21];

    float c0[20], c1[20];
    #pragma unroll
    for (int j = 0; j < 20; ++j) { c0[j] = 0.f; c1[j] = 0.f; h0p[j] = 0.f; h1p[j] = 0.f; }

    const float4* xp = (const float4*)(x + (size_t)b * 24);
    float acc[80];  // gate pre-activations: [0,20)=i [20,40)=f [40,60)=g [60,80)=o

    #pragma unroll 1
    for (int t = 0; t < 6; ++t) {
        float at = stats[t], bt = stats[6 + t];   // uniform -> SGPR
        float4 xv = xp[t];
        float xn[4];
        xn[0] = at * xv.x + bt; xn[1] = at * xv.y + bt;
        xn[2] = at * xv.z + bt; xn[3] = at * xv.w + bt;

        // ---- layer 0 ----
        #pragma unroll
        for (int j = 0; j < 80; ++j) acc[j] = wsT[OFF_B0 + j];
        #pragma unroll
        for (int k = 0; k < 4; ++k) {
            float s = xn[k];
            const float* w = wsT + OFF_IH0 + k * 80;
            #pragma unroll
            for (int j = 0; j < 80; ++j) acc[j] = fmaf(s, w[j], acc[j]);
        }
        #pragma unroll 2
        for (int k = 0; k < 20; ++k) {
            float s = h0p[k];
            const float* w = wsT + OFF_HH0 + k * 80;
            #pragma unroll
            for (int j = 0; j < 80; ++j) acc[j] = fmaf(s, w[j], acc[j]);
        }
        #pragma unroll
        for (int j = 0; j < 20; ++j) {
            float ii = sigm(acc[j]), ff = sigm(acc[20 + j]);
            float gg = tanh_f(acc[40 + j]), oo = sigm(acc[60 + j]);
            c0[j] = ff * c0[j] + ii * gg;
            h0p[j] = oo * tanh_f(c0[j]);
        }

        // ---- layer 1 ----
        #pragma unroll
        for (int j = 0; j < 80; ++j) acc[j] = wsT[OFF_B1 + j];
        #pragma unroll 2
        for (int k = 0; k < 20; ++k) {
            float s = h0p[k];
            const float* w = wsT + OFF_IH1 + k * 80;
            #pragma unroll
            for (int j = 0; j < 80; ++j) acc[j] = fmaf(s, w[j], acc[j]);
        }
        #pragma unroll 2
        for (int k = 0; k < 20; ++k) {
            float s = h1p[k];
            const float* w = wsT + OFF_HH1 + k * 80;
            #pragma unroll
            for (int j = 0; j < 80; ++j) acc[j] = fmaf(s, w[j], acc[j]);
        }
        #pragma unroll
        for (int j = 0; j < 20; ++j) {
            float ii = sigm(acc[j]), ff = sigm(acc[20 + j]);
            float gg = tanh_f(acc[40 + j]), oo = sigm(acc[60 + j]);
            c1[j] = ff * c1[j] + ii * gg;
            h1p[j] = oo * tanh_f(c1[j]);
        }
    }

    // final h2[:,5,:]: head dot + BN2 partial sums
    float sum = 0.f, sumsq = 0.f, dot = 0.f;
    #pragma unroll
    for (int j = 0; j < 20; ++j) {
        float v = h1p[j];
        sum += v; sumsq += v * v;
        dot = fmaf(v, Wout[j], dot);   // Wout uniform -> SGPR
    }
    dotout[b] = dot;
    sum = wave_reduce(sum);
    sumsq = wave_reduce(sumsq);
    __syncthreads();                    // all waves done with sH0 -> reuse as scratch
    float* red = sH0;
    int wid = tid >> 6, lane = tid & 63;
    if (lane == 0) { red[wid] = sum; red[4 + wid] = sumsq; }
    __syncthreads();
    if (tid == 0) {
        part2[blockIdx.x * 2 + 0] = red[0] + red[1] + red[2] + red[3];
        part2[blockIdx.x * 2 + 1] = red[4] + red[5] + red[6] + red[7];
    }
}

// ---------------- Kernel 4: finalize BN2 stats -> s1, s2 ----------------
__global__ __launch_bounds__(BLK) void k_stats2(const float* __restrict__ part2,
                                                const float* __restrict__ gamma,
                                                const float* __restrict__ beta,
                                                const float* __restrict__ Wout,
                                                const float* __restrict__ bout,
                                                float* __restrict__ stats) {
    float s = 0.f, q = 0.f;
    for (int p = threadIdx.x; p < NBLK; p += BLK) {
        s += part2[2 * p]; q += part2[2 * p + 1];
    }
    __shared__ float red[8];
    s = wave_reduce(s);
    q = wave_reduce(q);
    int wid = threadIdx.x >> 6, lane = threadIdx.x & 63;
    if (lane == 0) { red[wid] = s; red[4 + wid] = q; }
    __syncthreads();
    if (threadIdx.x == 0) {
        float S = red[0] + red[1] + red[2] + red[3];
        float Q = red[4] + red[5] + red[6] + red[7];
        const float N = (float)BATCH * 20.0f;
        float m = S / N, var = Q / N - m * m;
        float inv = rsqrtf(var + EPS);
        float s1 = gamma[5] * inv;
        float sw = 0.f;
        for (int h = 0; h < 20; ++h) sw += Wout[h];
        stats[12] = s1;
        stats[13] = (beta[5] - m * s1) * sw + bout[0];
    }
}

// ---------------- Kernel 5: out = s1*dot + s2 (in place) ----------------
__global__ __launch_bounds__(BLK) void k_out(float* __restrict__ out,
                                             const float* __restrict__ stats) {
    int i = blockIdx.x * BLK + threadIdx.x;
    out[i] = stats[12] * out[i] + stats[13];
}

extern "C" void kernel_launch(void* const* d_in, const int* in_sizes, int n_in,
                              void* d_out, int out_size, void* d_ws, size_t ws_size,
                              hipStream_t stream) {
    const float* x     = (const float*)d_in[0];
    const float* gamma = (const float*)d_in[1];
    const float* beta  = (const float*)d_in[2];
    const float* Wih0  = (const float*)d_in[3];
    const float* Whh0  = (const float*)d_in[4];
    const float* bih0  = (const float*)d_in[5];
    const float* bhh0  = (const float*)d_in[6];
    const float* Wih1  = (const float*)d_in[7];
    const float* Whh1  = (const float*)d_in[8];
    const float* bih1  = (const float*)d_in[9];
    const float* bhh1  = (const float*)d_in[10];
    const float* Wout  = (const float*)d_in[11];
    const float* bout  = (const float*)d_in[12];
    float* out = (float*)d_out;
    float* ws = (float*)d_ws;

    float* part1 = ws + OFF_P1;
    float* part2 = ws + OFF_P2;
    float* stats = ws + OFF_ST;

    k_prep<<<1, BLK, 0, stream>>>(Wih0, Whh0, bih0, bhh0,
                                  Wih1, Whh1, bih1, bhh1, ws);
    k_reduce_x<<<RBLK, BLK, 0, stream>>>(x, part1);
    k_stats1<<<1, BLK, 0, stream>>>(part1, gamma, beta, stats);
    k_lstm<<<NBLK, BLK, 0, stream>>>(x, ws, Wout, stats, out, part2);
    k_stats2<<<1, BLK, 0, stream>>>(part2, gamma, beta, Wout, bout, stats);
    k_out<<<NBLK, BLK, 0, stream>>>(out, stats);
}